// Round 13
// baseline (481.083 us; speedup 1.0000x reference)
//
#include <hip/hip_runtime.h>
#include <math.h>

#define N_TOT 4194304      // 64*256*256
#define CONV_BLOCKS 1024   // 16 co-groups x 64 tiles (32x32)
#define XS_PAD 4864        // 19 slots x 256 threads (cells >=4624 junk)

__device__ __forceinline__ float sgnf(float x) {
    return x > 0.f ? 1.f : (x < 0.f ? -1.f : 0.f);
}

__device__ __forceinline__ float gelu_f(float v) {
    const float c0 = 0.7978845608028654f;
    float inner = c0 * fmaf(0.044715f * v, v * v, v);
    return 0.5f * v * (1.f + tanhf(inner));
}

// async HBM->LDS, 4 bytes/lane. LDS dest = wave-uniform base + lane*4;
// all lanes must stay active (exec mask shifts the readfirstlane'd base).
__device__ __forceinline__ void gll4(const float* g, float* l) {
    __builtin_amdgcn_global_load_lds((const __attribute__((address_space(1))) void*)g,
                                     (__attribute__((address_space(3))) void*)l, 4, 0, 0);
}

// ---------------------------------------------------------------------------
// Kernel A: per-channel Hopfield fixed-point -> alpha[c] = bp_c . v5
// sign(q*bp) factors: sign(W@(s*v)) = s*sign(W@v) for s=+-1, so the 5-iter
// recurrence is pixel-independent. y = q + sgn(q)*alpha[c].
// ---------------------------------------------------------------------------
__global__ __launch_bounds__(64) void alpha_kernel(const float* __restrict__ bp,
                                                   const float* __restrict__ Wm,
                                                   float* __restrict__ alpha) {
    const int c = blockIdx.x, d = threadIdx.x;
    __shared__ float v[64];
    float bpv = bp[c * 64 + d];
    v[d] = sgnf(bpv);
    __syncthreads();
    const float* row = Wm + c * 4096 + d * 64;
    for (int it = 0; it < 5; ++it) {
        float s = 0.f;
        #pragma unroll
        for (int e = 0; e < 64; ++e) s = fmaf(row[e], v[e], s);
        __syncthreads();
        v[d] = sgnf(s);
        __syncthreads();
    }
    float val = bpv * v[d];
    #pragma unroll
    for (int off = 32; off; off >>= 1) val += __shfl_down(val, off);
    if (d == 0) alpha[c] = val;
}

// ---------------------------------------------------------------------------
// Kernel B: 3x3 SAME conv (fp32) + bias + fused y = q + sgn(q)*alpha[c].
// SINGLE-buffered LDS (19.5KB) -> 8 blocks/CU = 32 waves/CU: latency hiding
// moves from intra-block double-buffering to inter-block TLP (R12 was
// occupancy-capped at ~2.5 waves/SIMD by its 39KB dbuf; theory = latency-
// bound, so 4x wave parallelism should close the stall fraction).
// Everything else identical to R12: 2x2 paired micro-tile (rows 2ty,2ty+1;
// cols 2tx,2tx+1) x 4 co, b64 taps, wave-uniform weight s_loads, gll
// staging with 19 full unmasked slots + zero-page OOB.
// ---------------------------------------------------------------------------
__global__ __launch_bounds__(256, 8) void conv_kernel(const float* __restrict__ x,
                                                      const float* __restrict__ cw,
                                                      const float* __restrict__ cb,
                                                      const float* __restrict__ alpha,
                                                      const float* __restrict__ zbuf,
                                                      float* __restrict__ y,
                                                      double* __restrict__ partials) {
    const int tid = threadIdx.x;
    const int b = blockIdx.x;
    const int tile = b & 63;
    const int cog = b >> 6;                   // 4 output channels per group
    const int bx = tile & 7, by = tile >> 3;  // 8x8 tiles of 32x32
    const int tx = tid & 15, ty = tid >> 4;   // cols 2tx,2tx+1; rows 2ty,2ty+1

    __shared__ float xs[XS_PAD];              // [r*136 + ci*34 + c] single buf
    __shared__ double red[4][2];

    // ---- staging descriptors (19 full slots), computed once ----
    int voff[19];
    unsigned vmask = 0u;
    #pragma unroll
    for (int i = 0; i < 19; ++i) {
        int idx = i * 256 + tid;
        int r = idx / 136;
        int rem = idx - r * 136;
        int ci = rem / 34;
        int c = rem - ci * 34;
        int gy = (by << 5) - 1 + r;
        int gx = (bx << 5) + c - 1;
        bool ok = (idx < 4624) && ((unsigned)gy < 256u) && ((unsigned)gx < 256u);
        voff[i] = (ci << 16) + (gy << 8) + gx;
        if (ok) vmask |= (1u << i);
    }

    float acc[4][2][2];                       // [co][dy][col j]
    #pragma unroll
    for (int co = 0; co < 4; ++co) {
        float bias = cb[cog * 4 + co];
        acc[co][0][0] = bias; acc[co][0][1] = bias;
        acc[co][1][0] = bias; acc[co][1][1] = bias;
    }

    // prologue: stage slab 0 (all lanes; OOB lanes pull zeros)
    #pragma unroll
    for (int i = 0; i < 19; ++i) {
        const float* src = (vmask & (1u << i)) ? (x + voff[i]) : zbuf;
        gll4(src, &xs[i * 256 + tid]);
    }
    __syncthreads();                          // vmcnt drain -> slab 0 ready

    const int lrow = (2 * ty) * 136 + 2 * tx; // even dword -> 8B aligned
    const float* wbase = cw + cog * 4 * 576;

    for (int s = 0; s < 16; ++s) {
        #pragma unroll
        for (int ci = 0; ci < 4; ++ci) {
            float t[4][4];                    // 4 window rows x 4 cols
            #pragma unroll
            for (int rr = 0; rr < 4; ++rr) {
                const int off = lrow + rr * 136 + ci * 34;   // even
                float2 a = *reinterpret_cast<const float2*>(&xs[off]);
                float2 bb = *reinterpret_cast<const float2*>(&xs[off + 2]);
                t[rr][0] = a.x; t[rr][1] = a.y; t[rr][2] = bb.x; t[rr][3] = bb.y;
            }
            const float* wp = wbase + (s * 4 + ci) * 9;
            #pragma unroll
            for (int co = 0; co < 4; ++co) {
                const float* w = wp + co * 576;     // wave-uniform -> s_load
                #pragma unroll
                for (int ky = 0; ky < 3; ++ky)
                    #pragma unroll
                    for (int kx = 0; kx < 3; ++kx) {
                        float wv = w[ky * 3 + kx];
                        #pragma unroll
                        for (int dy = 0; dy < 2; ++dy)
                            #pragma unroll
                            for (int j = 0; j < 2; ++j)
                                acc[co][dy][j] = fmaf(wv, t[dy + ky][kx + j], acc[co][dy][j]);
                    }
            }
        }
        if (s < 15) {
            __syncthreads();                  // slab-s reads complete
            const float* xb = x + ((s + 1) << 18);   // +4 input channels
            #pragma unroll
            for (int i = 0; i < 19; ++i) {
                const float* src = (vmask & (1u << i)) ? (xb + voff[i]) : zbuf;
                gll4(src, &xs[i * 256 + tid]);
            }
            __syncthreads();                  // vmcnt drained -> slab s+1 ready
        }
    }

    // epilogue: y = q + sgn(q)*alpha, aligned float2 stores + f64 sums
    double s1 = 0.0, s2 = 0.0;
    const int gx0 = (bx << 5) + 2 * tx;
    const int gy0 = (by << 5) + 2 * ty;
    #pragma unroll
    for (int co = 0; co < 4; ++co) {
        float a = alpha[cog * 4 + co];
        const int cb_off = (cog * 4 + co) << 16;
        #pragma unroll
        for (int dy = 0; dy < 2; ++dy) {
            float q0 = acc[co][dy][0];
            float q1 = acc[co][dy][1];
            float y0v = q0 + (q0 > 0.f ? a : (q0 < 0.f ? -a : 0.f));
            float y1v = q1 + (q1 > 0.f ? a : (q1 < 0.f ? -a : 0.f));
            float2 pk; pk.x = y0v; pk.y = y1v;
            *reinterpret_cast<float2*>(&y[cb_off + ((gy0 + dy) << 8) + gx0]) = pk;
            s1 += (double)y0v + (double)y1v;
            s2 += (double)y0v * (double)y0v + (double)y1v * (double)y1v;
        }
    }
    #pragma unroll
    for (int off = 32; off; off >>= 1) {
        s1 += __shfl_down(s1, off);
        s2 += __shfl_down(s2, off);
    }
    const int wid = tid >> 6;
    if ((tid & 63) == 0) { red[wid][0] = s1; red[wid][1] = s2; }
    __syncthreads();
    if (tid == 0) {
        double a1 = red[0][0] + red[1][0] + red[2][0] + red[3][0];
        double a2 = red[0][1] + red[1][1] + red[2][1] + red[3][1];
        partials[b * 2]     = a1;
        partials[b * 2 + 1] = a2;
    }
}

// ---------------------------------------------------------------------------
// Kernel C: reduce CONV_BLOCKS partial pairs -> mean, inv_std (deterministic)
// ---------------------------------------------------------------------------
__global__ __launch_bounds__(256) void stats_kernel(const double* __restrict__ partials,
                                                    float* __restrict__ stats) {
    const int tid = threadIdx.x;
    double s1 = 0.0, s2 = 0.0;
    for (int i = tid; i < CONV_BLOCKS; i += 256) {
        s1 += partials[2 * i];
        s2 += partials[2 * i + 1];
    }
    #pragma unroll
    for (int off = 32; off; off >>= 1) {
        s1 += __shfl_down(s1, off);
        s2 += __shfl_down(s2, off);
    }
    __shared__ double red[4][2];
    const int wid = tid >> 6;
    if ((tid & 63) == 0) { red[wid][0] = s1; red[wid][1] = s2; }
    __syncthreads();
    if (tid == 0) {
        double a1 = red[0][0] + red[1][0] + red[2][0] + red[3][0];
        double a2 = red[0][1] + red[1][1] + red[2][1] + red[3][1];
        double mean = a1 / (double)N_TOT;
        double var = a2 / (double)N_TOT - mean * mean;
        stats[0] = (float)mean;
        stats[1] = (float)(1.0 / sqrt(var + 1e-5));
    }
}

// ---------------------------------------------------------------------------
// Kernel D: in-place norm-affine + gelu, float4 vectorized
// ---------------------------------------------------------------------------
__global__ __launch_bounds__(256) void finalize_kernel(float* __restrict__ y,
                                                       const float* __restrict__ stats,
                                                       const float* __restrict__ gnw,
                                                       const float* __restrict__ gnb) {
    const int i = blockIdx.x * 256 + threadIdx.x;  // float4 index
    const float mean = stats[0], istd = stats[1];
    const int c = i >> 14;
    const float scale = gnw[c] * istd;
    const float shift = gnb[c] - mean * scale;
    float4 v = reinterpret_cast<float4*>(y)[i];
    v.x = gelu_f(fmaf(v.x, scale, shift));
    v.y = gelu_f(fmaf(v.y, scale, shift));
    v.z = gelu_f(fmaf(v.z, scale, shift));
    v.w = gelu_f(fmaf(v.w, scale, shift));
    reinterpret_cast<float4*>(y)[i] = v;
}

extern "C" void kernel_launch(void* const* d_in, const int* in_sizes, int n_in,
                              void* d_out, int out_size, void* d_ws, size_t ws_size,
                              hipStream_t stream) {
    const float* x   = (const float*)d_in[0];
    const float* cw  = (const float*)d_in[1];
    const float* cb  = (const float*)d_in[2];
    const float* bp  = (const float*)d_in[3];
    const float* Wm  = (const float*)d_in[4];
    const float* gnw = (const float*)d_in[5];
    const float* gnb = (const float*)d_in[6];
    float* out = (float*)d_out;

    char* ws = (char*)d_ws;
    float* alpha     = (float*)ws;            // 64 floats
    float* stats     = (float*)(ws + 256);    // 2 floats
    double* partials = (double*)(ws + 512);   // CONV_BLOCKS*2 doubles
    float* zbuf      = (float*)(ws + 32768);  // 256B zero page for OOB lanes

    hipMemsetAsync(zbuf, 0, 256, stream);
    alpha_kernel<<<64, 64, 0, stream>>>(bp, Wm, alpha);
    conv_kernel<<<CONV_BLOCKS, 256, 0, stream>>>(x, cw, cb, alpha, zbuf, out, partials);
    stats_kernel<<<1, 256, 0, stream>>>(partials, stats);
    finalize_kernel<<<4096, 256, 0, stream>>>(out, stats, gnw, gnb);
}

// Round 14
// 108.839 us; speedup vs baseline: 4.4201x; 4.4201x over previous
//
#include <hip/hip_runtime.h>
#include <math.h>

#define N_TOT 4194304      // 64*256*256
#define CONV_BLOCKS 2048   // 16 co-groups x 128 tiles (32x16)
#define XS_DW 2560         // 10 slots x 256 thr; cells >=2448 junk pad

__device__ __forceinline__ float sgnf(float x) {
    return x > 0.f ? 1.f : (x < 0.f ? -1.f : 0.f);
}

__device__ __forceinline__ float gelu_f(float v) {
    const float c0 = 0.7978845608028654f;
    float inner = c0 * fmaf(0.044715f * v, v * v, v);
    return 0.5f * v * (1.f + tanhf(inner));
}

// async HBM->LDS, 4 bytes/lane. LDS dest = wave-uniform base + lane*4;
// all lanes must stay active (exec mask shifts the readfirstlane'd base).
__device__ __forceinline__ void gll4(const float* g, float* l) {
    __builtin_amdgcn_global_load_lds((const __attribute__((address_space(1))) void*)g,
                                     (__attribute__((address_space(3))) void*)l, 4, 0, 0);
}

// ---------------------------------------------------------------------------
// Kernel A: per-channel Hopfield fixed-point -> alpha[c] = bp_c . v5
// sign(q*bp) factors: sign(W@(s*v)) = s*sign(W@v) for s=+-1, so the 5-iter
// recurrence is pixel-independent. y = q + sgn(q)*alpha[c].
// ---------------------------------------------------------------------------
__global__ __launch_bounds__(64) void alpha_kernel(const float* __restrict__ bp,
                                                   const float* __restrict__ Wm,
                                                   float* __restrict__ alpha) {
    const int c = blockIdx.x, d = threadIdx.x;
    __shared__ float v[64];
    float bpv = bp[c * 64 + d];
    v[d] = sgnf(bpv);
    __syncthreads();
    const float* row = Wm + c * 4096 + d * 64;
    for (int it = 0; it < 5; ++it) {
        float s = 0.f;
        #pragma unroll
        for (int e = 0; e < 64; ++e) s = fmaf(row[e], v[e], s);
        __syncthreads();
        v[d] = sgnf(s);
        __syncthreads();
    }
    float val = bpv * v[d];
    #pragma unroll
    for (int off = 32; off; off >>= 1) val += __shfl_down(val, off);
    if (d == 0) alpha[c] = val;
}

// ---------------------------------------------------------------------------
// Kernel B: 3x3 SAME conv (fp32) + bias + fused y = q + sgn(q)*alpha[c].
// 32x16 tile x 4 co -> grid 2048 = 8 blocks/CU (R12's grid of 1024 capped
// residency at 4 blocks/CU = 31% occupancy; this was the real limiter).
// Thread: 1 row x 2 paired cols (2tx,2tx+1) x 4 co; taps = 2 aligned
// ds_read_b64 per window row (R12-proven pattern). Weights: wave-uniform
// s_loads. Staging: gll dbuf prefetch, 10 full unmasked slots, zero-page
// OOB. LDS = 2x2560 dw = 20480B exactly -> 8 blocks/CU; red[] aliases
// buf1's junk pad (staged-only region, read after all staging done).
// Grid: cog(16) x tile(128); same-tile blocks differ by 128 -> same XCD.
// ---------------------------------------------------------------------------
__global__ __launch_bounds__(256, 4) void conv_kernel(const float* __restrict__ x,
                                                      const float* __restrict__ cw,
                                                      const float* __restrict__ cb,
                                                      const float* __restrict__ alpha,
                                                      const float* __restrict__ zbuf,
                                                      float* __restrict__ y,
                                                      double* __restrict__ partials) {
    const int tid = threadIdx.x;
    const int b = blockIdx.x;
    const int tile = b & 127;
    const int cog = b >> 7;                   // 4 output channels per group
    const int bx = tile & 7, by = tile >> 3;  // 8 col-tiles x 16 row-tiles
    const int tx = tid & 15, ty = tid >> 4;   // cols 2tx,2tx+1; row ty

    __shared__ float xs[2][XS_DW];            // [buf][r*136 + ci*34 + c]
    double* red = (double*)&xs[1][2448];      // 8 doubles in buf1 junk pad

    // ---- staging descriptors (10 full slots), computed once ----
    int voff[10];
    unsigned vmask = 0u;
    #pragma unroll
    for (int i = 0; i < 10; ++i) {
        int idx = i * 256 + tid;
        int r = idx / 136;
        int rem = idx - r * 136;
        int ci = rem / 34;
        int c = rem - ci * 34;
        int gy = (by << 4) - 1 + r;
        int gx = (bx << 5) + c - 1;
        bool ok = (idx < 2448) && ((unsigned)gy < 256u) && ((unsigned)gx < 256u);
        voff[i] = (ci << 16) + (gy << 8) + gx;
        if (ok) vmask |= (1u << i);
    }

    float acc[4][2];                          // [co][col j]
    #pragma unroll
    for (int co = 0; co < 4; ++co) {
        float bias = cb[cog * 4 + co];
        acc[co][0] = bias; acc[co][1] = bias;
    }

    // prologue: stage slab 0 into buf 0 (all lanes; OOB lanes pull zeros)
    #pragma unroll
    for (int i = 0; i < 10; ++i) {
        const float* src = (vmask & (1u << i)) ? (x + voff[i]) : zbuf;
        gll4(src, &xs[0][i * 256 + tid]);
    }
    __syncthreads();                          // vmcnt drain -> slab 0 ready

    const int lrow = ty * 136 + 2 * tx;       // even dword -> 8B aligned
    const float* wbase = cw + cog * 4 * 576;

    for (int s = 0; s < 16; ++s) {
        const int cur = s & 1;
        // prefetch slab s+1 into the other buffer (overlaps compute below)
        if (s < 15) {
            const float* xb = x + ((s + 1) << 18);   // +4 input channels
            #pragma unroll
            for (int i = 0; i < 10; ++i) {
                const float* src = (vmask & (1u << i)) ? (xb + voff[i]) : zbuf;
                gll4(src, &xs[cur ^ 1][i * 256 + tid]);
            }
        }

        const float* xsc = xs[cur];
        #pragma unroll
        for (int ci = 0; ci < 4; ++ci) {
            float t[3][4];                    // 3 window rows x 4 cols
            #pragma unroll
            for (int rr = 0; rr < 3; ++rr) {
                const int off = lrow + rr * 136 + ci * 34;   // even
                float2 a = *reinterpret_cast<const float2*>(&xsc[off]);
                float2 bb = *reinterpret_cast<const float2*>(&xsc[off + 2]);
                t[rr][0] = a.x; t[rr][1] = a.y; t[rr][2] = bb.x; t[rr][3] = bb.y;
            }
            const float* wp = wbase + (s * 4 + ci) * 9;
            #pragma unroll
            for (int co = 0; co < 4; ++co) {
                const float* w = wp + co * 576;     // wave-uniform -> s_load
                #pragma unroll
                for (int ky = 0; ky < 3; ++ky)
                    #pragma unroll
                    for (int kx = 0; kx < 3; ++kx) {
                        float wv = w[ky * 3 + kx];
                        #pragma unroll
                        for (int j = 0; j < 2; ++j)
                            acc[co][j] = fmaf(wv, t[ky][kx + j], acc[co][j]);
                    }
            }
        }
        __syncthreads();   // compute-s reads done + prefetch s+1 landed
    }

    // epilogue: y = q + sgn(q)*alpha, aligned float2 stores + f64 sums
    double s1 = 0.0, s2 = 0.0;
    const int row = (by << 4) + ty;
    const int col0 = (bx << 5) + 2 * tx;
    #pragma unroll
    for (int co = 0; co < 4; ++co) {
        float a = alpha[cog * 4 + co];
        float q0 = acc[co][0];
        float q1 = acc[co][1];
        float y0v = q0 + (q0 > 0.f ? a : (q0 < 0.f ? -a : 0.f));
        float y1v = q1 + (q1 > 0.f ? a : (q1 < 0.f ? -a : 0.f));
        float2 pk; pk.x = y0v; pk.y = y1v;
        *reinterpret_cast<float2*>(&y[((cog * 4 + co) << 16) + (row << 8) + col0]) = pk;
        s1 += (double)y0v + (double)y1v;
        s2 += (double)y0v * (double)y0v + (double)y1v * (double)y1v;
    }
    #pragma unroll
    for (int off = 32; off; off >>= 1) {
        s1 += __shfl_down(s1, off);
        s2 += __shfl_down(s2, off);
    }
    const int wid = tid >> 6;
    if ((tid & 63) == 0) { red[wid * 2] = s1; red[wid * 2 + 1] = s2; }
    __syncthreads();
    if (tid == 0) {
        double a1 = red[0] + red[2] + red[4] + red[6];
        double a2 = red[1] + red[3] + red[5] + red[7];
        partials[b * 2]     = a1;
        partials[b * 2 + 1] = a2;
    }
}

// ---------------------------------------------------------------------------
// Kernel C: reduce CONV_BLOCKS partial pairs -> mean, inv_std (deterministic)
// ---------------------------------------------------------------------------
__global__ __launch_bounds__(256) void stats_kernel(const double* __restrict__ partials,
                                                    float* __restrict__ stats) {
    const int tid = threadIdx.x;
    double s1 = 0.0, s2 = 0.0;
    for (int i = tid; i < CONV_BLOCKS; i += 256) {
        s1 += partials[2 * i];
        s2 += partials[2 * i + 1];
    }
    #pragma unroll
    for (int off = 32; off; off >>= 1) {
        s1 += __shfl_down(s1, off);
        s2 += __shfl_down(s2, off);
    }
    __shared__ double red[4][2];
    const int wid = tid >> 6;
    if ((tid & 63) == 0) { red[wid][0] = s1; red[wid][1] = s2; }
    __syncthreads();
    if (tid == 0) {
        double a1 = red[0][0] + red[1][0] + red[2][0] + red[3][0];
        double a2 = red[0][1] + red[1][1] + red[2][1] + red[3][1];
        double mean = a1 / (double)N_TOT;
        double var = a2 / (double)N_TOT - mean * mean;
        stats[0] = (float)mean;
        stats[1] = (float)(1.0 / sqrt(var + 1e-5));
    }
}

// ---------------------------------------------------------------------------
// Kernel D: in-place norm-affine + gelu, float4 vectorized
// ---------------------------------------------------------------------------
__global__ __launch_bounds__(256) void finalize_kernel(float* __restrict__ y,
                                                       const float* __restrict__ stats,
                                                       const float* __restrict__ gnw,
                                                       const float* __restrict__ gnb) {
    const int i = blockIdx.x * 256 + threadIdx.x;  // float4 index
    const float mean = stats[0], istd = stats[1];
    const int c = i >> 14;
    const float scale = gnw[c] * istd;
    const float shift = gnb[c] - mean * scale;
    float4 v = reinterpret_cast<float4*>(y)[i];
    v.x = gelu_f(fmaf(v.x, scale, shift));
    v.y = gelu_f(fmaf(v.y, scale, shift));
    v.z = gelu_f(fmaf(v.z, scale, shift));
    v.w = gelu_f(fmaf(v.w, scale, shift));
    reinterpret_cast<float4*>(y)[i] = v;
}

extern "C" void kernel_launch(void* const* d_in, const int* in_sizes, int n_in,
                              void* d_out, int out_size, void* d_ws, size_t ws_size,
                              hipStream_t stream) {
    const float* x   = (const float*)d_in[0];
    const float* cw  = (const float*)d_in[1];
    const float* cb  = (const float*)d_in[2];
    const float* bp  = (const float*)d_in[3];
    const float* Wm  = (const float*)d_in[4];
    const float* gnw = (const float*)d_in[5];
    const float* gnb = (const float*)d_in[6];
    float* out = (float*)d_out;

    char* ws = (char*)d_ws;
    float* alpha     = (float*)ws;            // 64 floats
    float* stats     = (float*)(ws + 256);    // 2 floats
    double* partials = (double*)(ws + 512);   // CONV_BLOCKS*2 doubles (32KB)
    float* zbuf      = (float*)(ws + 36864);  // 256B zero page for OOB lanes

    hipMemsetAsync(zbuf, 0, 256, stream);
    alpha_kernel<<<64, 64, 0, stream>>>(bp, Wm, alpha);
    conv_kernel<<<CONV_BLOCKS, 256, 0, stream>>>(x, cw, cb, alpha, zbuf, out, partials);
    stats_kernel<<<1, 256, 0, stream>>>(partials, stats);
    finalize_kernel<<<4096, 256, 0, stream>>>(out, stats, gnw, gnb);
}

// Round 15
// 101.084 us; speedup vs baseline: 4.7592x; 1.0767x over previous
//
#include <hip/hip_runtime.h>
#include <math.h>

#define N_TOT 4194304      // 64*256*256
#define CONV_BLOCKS 1024   // 16 co-groups x 64 tiles (32x32)
#define XS_PAD 4864        // 19 slots x 256 threads (cells >=4624 junk)

__device__ __forceinline__ float sgnf(float x) {
    return x > 0.f ? 1.f : (x < 0.f ? -1.f : 0.f);
}

__device__ __forceinline__ float gelu_f(float v) {
    const float c0 = 0.7978845608028654f;
    float inner = c0 * fmaf(0.044715f * v, v * v, v);
    return 0.5f * v * (1.f + tanhf(inner));
}

// async HBM->LDS, 4 bytes/lane. LDS dest = wave-uniform base + lane*4;
// all lanes must stay active (exec mask shifts the readfirstlane'd base).
__device__ __forceinline__ void gll4(const float* g, float* l) {
    __builtin_amdgcn_global_load_lds((const __attribute__((address_space(1))) void*)g,
                                     (__attribute__((address_space(3))) void*)l, 4, 0, 0);
}

// ---------------------------------------------------------------------------
// Kernel A: per-channel Hopfield fixed-point -> alpha[c] = bp_c . v5
// sign(q*bp) factors: sign(W@(s*v)) = s*sign(W@v) for s=+-1, so the 5-iter
// recurrence is pixel-independent. y = q + sgn(q)*alpha[c].
// ---------------------------------------------------------------------------
__global__ __launch_bounds__(64) void alpha_kernel(const float* __restrict__ bp,
                                                   const float* __restrict__ Wm,
                                                   float* __restrict__ alpha) {
    const int c = blockIdx.x, d = threadIdx.x;
    __shared__ float v[64];
    float bpv = bp[c * 64 + d];
    v[d] = sgnf(bpv);
    __syncthreads();
    const float* row = Wm + c * 4096 + d * 64;
    for (int it = 0; it < 5; ++it) {
        float s = 0.f;
        #pragma unroll
        for (int e = 0; e < 64; ++e) s = fmaf(row[e], v[e], s);
        __syncthreads();
        v[d] = sgnf(s);
        __syncthreads();
    }
    float val = bpv * v[d];
    #pragma unroll
    for (int off = 32; off; off >>= 1) val += __shfl_down(val, off);
    if (d == 0) alpha[c] = val;
}

// load the 4x4 tap window for one ci into t (2 aligned b64 per row)
#define LOAD_T(T, XSC, CIOFF)                                                 \
    {                                                                         \
        _Pragma("unroll")                                                     \
        for (int rr = 0; rr < 4; ++rr) {                                      \
            const int off_ = lrow + rr * 136 + (CIOFF);                       \
            float2 a_ = *reinterpret_cast<const float2*>(&(XSC)[off_]);       \
            float2 b_ = *reinterpret_cast<const float2*>(&(XSC)[off_ + 2]);   \
            T[rr][0] = a_.x; T[rr][1] = a_.y; T[rr][2] = b_.x; T[rr][3] = b_.y;\
        }                                                                     \
    }

// 144 FMAs for one ci using window T and weight base WP (wave-uniform)
#define FMA_CI(T, WP)                                                         \
    {                                                                         \
        _Pragma("unroll")                                                     \
        for (int co = 0; co < 4; ++co) {                                      \
            const float* w_ = (WP) + co * 576;                                \
            _Pragma("unroll")                                                 \
            for (int ky = 0; ky < 3; ++ky)                                    \
                _Pragma("unroll")                                             \
                for (int kx = 0; kx < 3; ++kx) {                              \
                    float wv_ = w_[ky * 3 + kx];                              \
                    _Pragma("unroll")                                         \
                    for (int dy = 0; dy < 2; ++dy)                            \
                        _Pragma("unroll")                                     \
                        for (int j = 0; j < 2; ++j)                           \
                            acc[co][dy][j] = fmaf(wv_, T[dy + ky][kx + j],    \
                                                  acc[co][dy][j]);            \
                }                                                             \
        }                                                                     \
    }

// ---------------------------------------------------------------------------
// Kernel B: 3x3 SAME conv (fp32) + bias + fused y = q + sgn(q)*alpha[c].
// R12 structure (32x32 tile x 4 co, 2x2 paired micro-tile, b64 taps,
// gll double-buffered staging) + EXPLICIT ci SOFTWARE PIPELINE: taps for
// ci+1 are ds_read BEFORE the FMA block of ci (register double-buffer
// tA/tB, static indexing), so the ~120cy LDS latency and the weight
// s_load latency hide under 144 FMAs. launch_bounds(256,2): VGPR cap 128
// (LDS caps residency at 4 blocks/CU anyway).
// ---------------------------------------------------------------------------
__global__ __launch_bounds__(256, 2) void conv_kernel(const float* __restrict__ x,
                                                      const float* __restrict__ cw,
                                                      const float* __restrict__ cb,
                                                      const float* __restrict__ alpha,
                                                      const float* __restrict__ zbuf,
                                                      float* __restrict__ y,
                                                      double* __restrict__ partials) {
    const int tid = threadIdx.x;
    const int b = blockIdx.x;
    const int tile = b & 63;
    const int cog = b >> 6;                   // 4 output channels per group
    const int bx = tile & 7, by = tile >> 3;  // 8x8 tiles of 32x32
    const int tx = tid & 15, ty = tid >> 4;   // cols 2tx,2tx+1; rows 2ty,2ty+1

    __shared__ float xs[2][XS_PAD];           // [buf][r*136 + ci*34 + c]
    __shared__ double red[4][2];

    // ---- staging descriptors (19 full slots), computed once ----
    int voff[19];
    unsigned vmask = 0u;
    #pragma unroll
    for (int i = 0; i < 19; ++i) {
        int idx = i * 256 + tid;
        int r = idx / 136;
        int rem = idx - r * 136;
        int ci = rem / 34;
        int c = rem - ci * 34;
        int gy = (by << 5) - 1 + r;
        int gx = (bx << 5) + c - 1;
        bool ok = (idx < 4624) && ((unsigned)gy < 256u) && ((unsigned)gx < 256u);
        voff[i] = (ci << 16) + (gy << 8) + gx;
        if (ok) vmask |= (1u << i);
    }

    float acc[4][2][2];                       // [co][dy][col j]
    #pragma unroll
    for (int co = 0; co < 4; ++co) {
        float bias = cb[cog * 4 + co];
        acc[co][0][0] = bias; acc[co][0][1] = bias;
        acc[co][1][0] = bias; acc[co][1][1] = bias;
    }

    // prologue: stage slab 0 into buf 0 (all lanes; OOB lanes pull zeros)
    #pragma unroll
    for (int i = 0; i < 19; ++i) {
        const float* src = (vmask & (1u << i)) ? (x + voff[i]) : zbuf;
        gll4(src, &xs[0][i * 256 + tid]);
    }
    __syncthreads();                          // vmcnt drain -> slab 0 ready

    const int lrow = (2 * ty) * 136 + 2 * tx; // even dword -> 8B aligned
    const float* wbase = cw + cog * 4 * 576;

    float tA[4][4], tB[4][4];

    for (int s = 0; s < 16; ++s) {
        const int cur = s & 1;
        // prefetch slab s+1 into the other buffer (overlaps compute below)
        if (s < 15) {
            const float* xb = x + ((s + 1) << 18);   // +4 input channels
            #pragma unroll
            for (int i = 0; i < 19; ++i) {
                const float* src = (vmask & (1u << i)) ? (xb + voff[i]) : zbuf;
                gll4(src, &xs[cur ^ 1][i * 256 + tid]);
            }
        }

        const float* xsc = xs[cur];
        const float* wp = wbase + (s * 4) * 9;

        // software pipeline over ci = 0..3: load ci+1 taps before ci FMAs
        LOAD_T(tA, xsc, 0)                      // ci 0
        LOAD_T(tB, xsc, 34)                     // ci 1 (in flight over ci0 FMA)
        FMA_CI(tA, wp)                          // ci 0
        LOAD_T(tA, xsc, 68)                     // ci 2
        FMA_CI(tB, wp + 9)                      // ci 1
        LOAD_T(tB, xsc, 102)                    // ci 3
        FMA_CI(tA, wp + 18)                     // ci 2
        FMA_CI(tB, wp + 27)                     // ci 3

        __syncthreads();   // compute-s reads done + prefetch s+1 landed
    }

    // epilogue: y = q + sgn(q)*alpha, aligned float2 stores + f64 sums
    double s1 = 0.0, s2 = 0.0;
    const int gx0 = (bx << 5) + 2 * tx;
    const int gy0 = (by << 5) + 2 * ty;
    #pragma unroll
    for (int co = 0; co < 4; ++co) {
        float a = alpha[cog * 4 + co];
        const int cb_off = (cog * 4 + co) << 16;
        #pragma unroll
        for (int dy = 0; dy < 2; ++dy) {
            float q0 = acc[co][dy][0];
            float q1 = acc[co][dy][1];
            float y0v = q0 + (q0 > 0.f ? a : (q0 < 0.f ? -a : 0.f));
            float y1v = q1 + (q1 > 0.f ? a : (q1 < 0.f ? -a : 0.f));
            float2 pk; pk.x = y0v; pk.y = y1v;
            *reinterpret_cast<float2*>(&y[cb_off + ((gy0 + dy) << 8) + gx0]) = pk;
            s1 += (double)y0v + (double)y1v;
            s2 += (double)y0v * (double)y0v + (double)y1v * (double)y1v;
        }
    }
    #pragma unroll
    for (int off = 32; off; off >>= 1) {
        s1 += __shfl_down(s1, off);
        s2 += __shfl_down(s2, off);
    }
    const int wid = tid >> 6;
    if ((tid & 63) == 0) { red[wid][0] = s1; red[wid][1] = s2; }
    __syncthreads();
    if (tid == 0) {
        double a1 = red[0][0] + red[1][0] + red[2][0] + red[3][0];
        double a2 = red[0][1] + red[1][1] + red[2][1] + red[3][1];
        partials[b * 2]     = a1;
        partials[b * 2 + 1] = a2;
    }
}

// ---------------------------------------------------------------------------
// Kernel C: reduce CONV_BLOCKS partial pairs -> mean, inv_std (deterministic)
// ---------------------------------------------------------------------------
__global__ __launch_bounds__(256) void stats_kernel(const double* __restrict__ partials,
                                                    float* __restrict__ stats) {
    const int tid = threadIdx.x;
    double s1 = 0.0, s2 = 0.0;
    for (int i = tid; i < CONV_BLOCKS; i += 256) {
        s1 += partials[2 * i];
        s2 += partials[2 * i + 1];
    }
    #pragma unroll
    for (int off = 32; off; off >>= 1) {
        s1 += __shfl_down(s1, off);
        s2 += __shfl_down(s2, off);
    }
    __shared__ double red[4][2];
    const int wid = tid >> 6;
    if ((tid & 63) == 0) { red[wid][0] = s1; red[wid][1] = s2; }
    __syncthreads();
    if (tid == 0) {
        double a1 = red[0][0] + red[1][0] + red[2][0] + red[3][0];
        double a2 = red[0][1] + red[1][1] + red[2][1] + red[3][1];
        double mean = a1 / (double)N_TOT;
        double var = a2 / (double)N_TOT - mean * mean;
        stats[0] = (float)mean;
        stats[1] = (float)(1.0 / sqrt(var + 1e-5));
    }
}

// ---------------------------------------------------------------------------
// Kernel D: in-place norm-affine + gelu, float4 vectorized
// ---------------------------------------------------------------------------
__global__ __launch_bounds__(256) void finalize_kernel(float* __restrict__ y,
                                                       const float* __restrict__ stats,
                                                       const float* __restrict__ gnw,
                                                       const float* __restrict__ gnb) {
    const int i = blockIdx.x * 256 + threadIdx.x;  // float4 index
    const float mean = stats[0], istd = stats[1];
    const int c = i >> 14;
    const float scale = gnw[c] * istd;
    const float shift = gnb[c] - mean * scale;
    float4 v = reinterpret_cast<float4*>(y)[i];
    v.x = gelu_f(fmaf(v.x, scale, shift));
    v.y = gelu_f(fmaf(v.y, scale, shift));
    v.z = gelu_f(fmaf(v.z, scale, shift));
    v.w = gelu_f(fmaf(v.w, scale, shift));
    reinterpret_cast<float4*>(y)[i] = v;
}

extern "C" void kernel_launch(void* const* d_in, const int* in_sizes, int n_in,
                              void* d_out, int out_size, void* d_ws, size_t ws_size,
                              hipStream_t stream) {
    const float* x   = (const float*)d_in[0];
    const float* cw  = (const float*)d_in[1];
    const float* cb  = (const float*)d_in[2];
    const float* bp  = (const float*)d_in[3];
    const float* Wm  = (const float*)d_in[4];
    const float* gnw = (const float*)d_in[5];
    const float* gnb = (const float*)d_in[6];
    float* out = (float*)d_out;

    char* ws = (char*)d_ws;
    float* alpha     = (float*)ws;            // 64 floats
    float* stats     = (float*)(ws + 256);    // 2 floats
    double* partials = (double*)(ws + 512);   // CONV_BLOCKS*2 doubles
    float* zbuf      = (float*)(ws + 32768);  // 256B zero page for OOB lanes

    hipMemsetAsync(zbuf, 0, 256, stream);
    alpha_kernel<<<64, 64, 0, stream>>>(bp, Wm, alpha);
    conv_kernel<<<CONV_BLOCKS, 256, 0, stream>>>(x, cw, cb, alpha, zbuf, out, partials);
    stats_kernel<<<1, 256, 0, stream>>>(partials, stats);
    finalize_kernel<<<4096, 256, 0, stream>>>(out, stats, gnw, gnb);
}

// Round 17
// 91.579 us; speedup vs baseline: 5.2532x; 1.1038x over previous
//
#include <hip/hip_runtime.h>
#include <math.h>

#define N_TOT 4194304      // 64*256*256
#define CONV_BLOCKS 1024   // 16 co-groups x 64 tiles (32x32)
#define XS_DW 5120         // 1280 chunks x 4 dw (cells >=4896 junk pad)
#define PITCH 272          // padded x row pitch (dwords), 16B aligned
#define PROWS 258          // padded rows (-1..256)
#define PCI (PROWS * PITCH)        // 70176 dwords per channel
#define PAD_TOT (64 * PCI)         // 4491264 dwords
#define PAD_BYTES (PAD_TOT * 4)    // 17965056 B
#define WS_PAD_OFF 32768

__device__ __forceinline__ float sgnf(float x) {
    return x > 0.f ? 1.f : (x < 0.f ? -1.f : 0.f);
}

__device__ __forceinline__ float gelu_f(float v) {
    const float c0 = 0.7978845608028654f;
    float inner = c0 * fmaf(0.044715f * v, v * v, v);
    return 0.5f * v * (1.f + tanhf(inner));
}

// async HBM->LDS. LDS dest = wave-uniform base + lane*width; full waves only.
__device__ __forceinline__ void gll4(const float* g, float* l) {
    __builtin_amdgcn_global_load_lds((const __attribute__((address_space(1))) void*)g,
                                     (__attribute__((address_space(3))) void*)l, 4, 0, 0);
}
__device__ __forceinline__ void gll16(const float* g, float* l) {
    __builtin_amdgcn_global_load_lds((const __attribute__((address_space(1))) void*)g,
                                     (__attribute__((address_space(3))) void*)l, 16, 0, 0);
}

// ---------------------------------------------------------------------------
// Kernel A: per-channel Hopfield fixed-point -> alpha[c] = bp_c . v5
// sign(q*bp) factors: sign(W@(s*v)) = s*sign(W@v) for s=+-1, so the 5-iter
// recurrence is pixel-independent. y = q + sgn(q)*alpha[c].
// ---------------------------------------------------------------------------
__global__ __launch_bounds__(64) void alpha_kernel(const float* __restrict__ bp,
                                                   const float* __restrict__ Wm,
                                                   float* __restrict__ alpha) {
    const int c = blockIdx.x, d = threadIdx.x;
    __shared__ float v[64];
    float bpv = bp[c * 64 + d];
    v[d] = sgnf(bpv);
    __syncthreads();
    const float* row = Wm + c * 4096 + d * 64;
    for (int it = 0; it < 5; ++it) {
        float s = 0.f;
        #pragma unroll
        for (int e = 0; e < 64; ++e) s = fmaf(row[e], v[e], s);
        __syncthreads();
        v[d] = sgnf(s);
        __syncthreads();
    }
    float val = bpv * v[d];
    #pragma unroll
    for (int off = 32; off; off >>= 1) val += __shfl_down(val, off);
    if (d == 0) alpha[c] = val;
}

// ---------------------------------------------------------------------------
// Kernel P: zero-padded copy of x into ws: pad[ci][py(258)][px(272)],
// pad[ci][py][px] = x[ci][py-1][px-1] for 1<=py,px<=256 else 0.
// ---------------------------------------------------------------------------
__global__ __launch_bounds__(256) void pad_kernel(const float* __restrict__ x,
                                                  float* __restrict__ pad) {
    const int idx = blockIdx.x * 256 + threadIdx.x;   // < PAD_TOT (exact grid)
    const int ci = idx / PCI;
    int rem = idx - ci * PCI;
    const int py = rem / PITCH;
    const int px = rem - py * PITCH;
    float v = 0.f;
    if (py >= 1 && py <= 256 && px >= 1 && px <= 256)
        v = x[(ci << 16) + ((py - 1) << 8) + (px - 1)];
    pad[idx] = v;
}

// load the 4x4 tap window for one ci into t (2 aligned b64 per row)
#define LOAD_T(T, XSC, CIOFF)                                                 \
    {                                                                         \
        _Pragma("unroll")                                                     \
        for (int rr = 0; rr < 4; ++rr) {                                      \
            const int off_ = lrow + rr * 144 + (CIOFF);                       \
            float2 a_ = *reinterpret_cast<const float2*>(&(XSC)[off_]);       \
            float2 b_ = *reinterpret_cast<const float2*>(&(XSC)[off_ + 2]);   \
            T[rr][0] = a_.x; T[rr][1] = a_.y; T[rr][2] = b_.x; T[rr][3] = b_.y;\
        }                                                                     \
    }

// 144 FMAs for one ci using window T and weight base WP (wave-uniform)
#define FMA_CI(T, WP)                                                         \
    {                                                                         \
        _Pragma("unroll")                                                     \
        for (int co = 0; co < 4; ++co) {                                      \
            const float* w_ = (WP) + co * 576;                                \
            _Pragma("unroll")                                                 \
            for (int ky = 0; ky < 3; ++ky)                                    \
                _Pragma("unroll")                                             \
                for (int kx = 0; kx < 3; ++kx) {                              \
                    float wv_ = w_[ky * 3 + kx];                              \
                    _Pragma("unroll")                                         \
                    for (int dy = 0; dy < 2; ++dy)                            \
                        _Pragma("unroll")                                     \
                        for (int j = 0; j < 2; ++j)                           \
                            acc[co][dy][j] = fmaf(wv_, T[dy + ky][kx + j],    \
                                                  acc[co][dy][j]);            \
                }                                                             \
        }                                                                     \
    }

// ---------------------------------------------------------------------------
// Kernel B: 3x3 SAME conv (fp32) + bias + fused y = q + sgn(q)*alpha[c].
// Stages from PADDED x: no bounds checks, no masks, no zero page.
// Slab = 4 ci x 34 rows x 36 cols = 1224 16B-chunks (+56 junk) staged by
// FIVE gll16 slots (was 19 gll4 + 19 masks): descriptor state 19->5 VGPRs,
// 4x fewer VMEM instrs -> register headroom for the tA/tB ci-pipeline.
// LDS [r(34)][ci(4)][c(36)] stride 144; taps = R12-proven even-b64 pattern.
// LDS 2x20480B = exactly 4 blocks/CU; red[] aliases buf1 junk pad.
// ---------------------------------------------------------------------------
__global__ __launch_bounds__(256, 2) void conv_kernel(const float* __restrict__ xp,
                                                      const float* __restrict__ cw,
                                                      const float* __restrict__ cb,
                                                      const float* __restrict__ alpha,
                                                      float* __restrict__ y,
                                                      double* __restrict__ partials) {
    const int tid = threadIdx.x;
    const int b = blockIdx.x;
    const int tile = b & 63;
    const int cog = b >> 6;                   // 4 output channels per group
    const int bx = tile & 7, by = tile >> 3;  // 8x8 tiles of 32x32
    const int tx = tid & 15, ty = tid >> 4;   // cols 2tx,2tx+1; rows 2ty,2ty+1

    __shared__ float xs[2][XS_DW];            // [buf][r*144 + ci*36 + c]
    double* red = (double*)&xs[1][4896];      // 8 doubles in buf1 junk pad

    // ---- 5 chunk descriptors (global dword offsets), computed once ----
    int goff[5];
    #pragma unroll
    for (int i = 0; i < 5; ++i) {
        int c4 = i * 256 + tid;               // chunk id < 1280
        int r = c4 / 36;
        int rem = c4 - r * 36;
        int ci = rem / 9;
        int cc = rem - ci * 9;
        int g = ci * PCI + ((by << 5) + r) * PITCH + (bx << 5) + cc * 4;
        goff[i] = (c4 < 1224) ? g : 0;        // junk chunks read pad base
    }

    float acc[4][2][2];                       // [co][dy][col j]
    #pragma unroll
    for (int co = 0; co < 4; ++co) {
        float bias = cb[cog * 4 + co];
        acc[co][0][0] = bias; acc[co][0][1] = bias;
        acc[co][1][0] = bias; acc[co][1][1] = bias;
    }

    // prologue: stage slab 0 into buf 0
    #pragma unroll
    for (int i = 0; i < 5; ++i)
        gll16(xp + goff[i], &xs[0][(i * 256 + tid) * 4]);
    __syncthreads();                          // vmcnt drain -> slab 0 ready

    const int lrow = (2 * ty) * 144 + 2 * tx; // even dword -> 8B aligned
    const float* wbase = cw + cog * 4 * 576;

    float tA[4][4], tB[4][4];

    for (int s = 0; s < 16; ++s) {
        const int cur = s & 1;
        // prefetch slab s+1 into the other buffer (overlaps compute below)
        if (s < 15) {
            const float* xb = xp + (s + 1) * (4 * PCI);
            #pragma unroll
            for (int i = 0; i < 5; ++i)
                gll16(xb + goff[i], &xs[cur ^ 1][(i * 256 + tid) * 4]);
        }

        const float* xsc = xs[cur];
        const float* wp = wbase + (s * 4) * 9;

        // software pipeline over ci = 0..3: load ci+1 taps before ci FMAs
        LOAD_T(tA, xsc, 0)                      // ci 0
        LOAD_T(tB, xsc, 36)                     // ci 1 (in flight over ci0 FMA)
        FMA_CI(tA, wp)                          // ci 0
        LOAD_T(tA, xsc, 72)                     // ci 2
        FMA_CI(tB, wp + 9)                      // ci 1
        LOAD_T(tB, xsc, 108)                    // ci 3
        FMA_CI(tA, wp + 18)                     // ci 2
        FMA_CI(tB, wp + 27)                     // ci 3

        __syncthreads();   // compute-s reads done + prefetch s+1 landed
    }

    // epilogue: y = q + sgn(q)*alpha, aligned float2 stores + f64 sums
    double s1 = 0.0, s2 = 0.0;
    const int gx0 = (bx << 5) + 2 * tx;
    const int gy0 = (by << 5) + 2 * ty;
    #pragma unroll
    for (int co = 0; co < 4; ++co) {
        float a = alpha[cog * 4 + co];
        const int cb_off = (cog * 4 + co) << 16;
        #pragma unroll
        for (int dy = 0; dy < 2; ++dy) {
            float q0 = acc[co][dy][0];
            float q1 = acc[co][dy][1];
            float y0v = q0 + (q0 > 0.f ? a : (q0 < 0.f ? -a : 0.f));
            float y1v = q1 + (q1 > 0.f ? a : (q1 < 0.f ? -a : 0.f));
            float2 pk; pk.x = y0v; pk.y = y1v;
            *reinterpret_cast<float2*>(&y[cb_off + ((gy0 + dy) << 8) + gx0]) = pk;
            s1 += (double)y0v + (double)y1v;
            s2 += (double)y0v * (double)y0v + (double)y1v * (double)y1v;
        }
    }
    #pragma unroll
    for (int off = 32; off; off >>= 1) {
        s1 += __shfl_down(s1, off);
        s2 += __shfl_down(s2, off);
    }
    const int wid = tid >> 6;
    if ((tid & 63) == 0) { red[wid * 2] = s1; red[wid * 2 + 1] = s2; }
    __syncthreads();
    if (tid == 0) {
        double a1 = red[0] + red[2] + red[4] + red[6];
        double a2 = red[1] + red[3] + red[5] + red[7];
        partials[b * 2]     = a1;
        partials[b * 2 + 1] = a2;
    }
}

// ---------------------------------------------------------------------------
// Fallback conv (R15 path, no padded x) if ws is too small.
// ---------------------------------------------------------------------------
__global__ __launch_bounds__(256, 2) void conv_fb(const float* __restrict__ x,
                                                  const float* __restrict__ cw,
                                                  const float* __restrict__ cb,
                                                  const float* __restrict__ alpha,
                                                  const float* __restrict__ zbuf,
                                                  float* __restrict__ y,
                                                  double* __restrict__ partials) {
    const int tid = threadIdx.x;
    const int b = blockIdx.x;
    const int tile = b & 63;
    const int cog = b >> 6;
    const int bx = tile & 7, by = tile >> 3;
    const int tx = tid & 15, ty = tid >> 4;

    __shared__ float xs[2][4864];
    __shared__ double red[4][2];

    int voff[19];
    unsigned vmask = 0u;
    #pragma unroll
    for (int i = 0; i < 19; ++i) {
        int idx = i * 256 + tid;
        int r = idx / 136;
        int rem = idx - r * 136;
        int ci = rem / 34;
        int c = rem - ci * 34;
        int gy = (by << 5) - 1 + r;
        int gx = (bx << 5) + c - 1;
        bool ok = (idx < 4624) && ((unsigned)gy < 256u) && ((unsigned)gx < 256u);
        voff[i] = (ci << 16) + (gy << 8) + gx;
        if (ok) vmask |= (1u << i);
    }

    float acc[4][2][2];
    #pragma unroll
    for (int co = 0; co < 4; ++co) {
        float bias = cb[cog * 4 + co];
        acc[co][0][0] = bias; acc[co][0][1] = bias;
        acc[co][1][0] = bias; acc[co][1][1] = bias;
    }

    #pragma unroll
    for (int i = 0; i < 19; ++i) {
        const float* src = (vmask & (1u << i)) ? (x + voff[i]) : zbuf;
        gll4(src, &xs[0][i * 256 + tid]);
    }
    __syncthreads();

    const int lrow2 = (2 * ty) * 136 + 2 * tx;
    const float* wbase = cw + cog * 4 * 576;

    for (int s = 0; s < 16; ++s) {
        const int cur = s & 1;
        if (s < 15) {
            const float* xb = x + ((s + 1) << 18);
            #pragma unroll
            for (int i = 0; i < 19; ++i) {
                const float* src = (vmask & (1u << i)) ? (xb + voff[i]) : zbuf;
                gll4(src, &xs[cur ^ 1][i * 256 + tid]);
            }
        }
        const float* xsc = xs[cur];
        #pragma unroll
        for (int ci = 0; ci < 4; ++ci) {
            float t[4][4];
            #pragma unroll
            for (int rr = 0; rr < 4; ++rr) {
                const int off = lrow2 + rr * 136 + ci * 34;
                float2 a = *reinterpret_cast<const float2*>(&xsc[off]);
                float2 bb = *reinterpret_cast<const float2*>(&xsc[off + 2]);
                t[rr][0] = a.x; t[rr][1] = a.y; t[rr][2] = bb.x; t[rr][3] = bb.y;
            }
            const float* wp = wbase + (s * 4 + ci) * 9;
            #pragma unroll
            for (int co = 0; co < 4; ++co) {
                const float* w = wp + co * 576;
                #pragma unroll
                for (int ky = 0; ky < 3; ++ky)
                    #pragma unroll
                    for (int kx = 0; kx < 3; ++kx) {
                        float wv = w[ky * 3 + kx];
                        #pragma unroll
                        for (int dy = 0; dy < 2; ++dy)
                            #pragma unroll
                            for (int j = 0; j < 2; ++j)
                                acc[co][dy][j] = fmaf(wv, t[dy + ky][kx + j], acc[co][dy][j]);
                    }
            }
        }
        __syncthreads();
    }

    double s1 = 0.0, s2 = 0.0;
    const int gx0 = (bx << 5) + 2 * tx;
    const int gy0 = (by << 5) + 2 * ty;
    #pragma unroll
    for (int co = 0; co < 4; ++co) {
        float a = alpha[cog * 4 + co];
        const int cb_off = (cog * 4 + co) << 16;
        #pragma unroll
        for (int dy = 0; dy < 2; ++dy) {
            float q0 = acc[co][dy][0];
            float q1 = acc[co][dy][1];
            float y0v = q0 + (q0 > 0.f ? a : (q0 < 0.f ? -a : 0.f));
            float y1v = q1 + (q1 > 0.f ? a : (q1 < 0.f ? -a : 0.f));
            float2 pk; pk.x = y0v; pk.y = y1v;
            *reinterpret_cast<float2*>(&y[cb_off + ((gy0 + dy) << 8) + gx0]) = pk;
            s1 += (double)y0v + (double)y1v;
            s2 += (double)y0v * (double)y0v + (double)y1v * (double)y1v;
        }
    }
    #pragma unroll
    for (int off = 32; off; off >>= 1) {
        s1 += __shfl_down(s1, off);
        s2 += __shfl_down(s2, off);
    }
    const int wid = tid >> 6;
    if ((tid & 63) == 0) { red[wid][0] = s1; red[wid][1] = s2; }
    __syncthreads();
    if (tid == 0) {
        partials[b * 2]     = red[0][0] + red[1][0] + red[2][0] + red[3][0];
        partials[b * 2 + 1] = red[0][1] + red[1][1] + red[2][1] + red[3][1];
    }
}

// ---------------------------------------------------------------------------
// Kernel C: reduce CONV_BLOCKS partial pairs -> mean, inv_std (deterministic)
// ---------------------------------------------------------------------------
__global__ __launch_bounds__(256) void stats_kernel(const double* __restrict__ partials,
                                                    float* __restrict__ stats) {
    const int tid = threadIdx.x;
    double s1 = 0.0, s2 = 0.0;
    for (int i = tid; i < CONV_BLOCKS; i += 256) {
        s1 += partials[2 * i];
        s2 += partials[2 * i + 1];
    }
    #pragma unroll
    for (int off = 32; off; off >>= 1) {
        s1 += __shfl_down(s1, off);
        s2 += __shfl_down(s2, off);
    }
    __shared__ double red[4][2];
    const int wid = tid >> 6;
    if ((tid & 63) == 0) { red[wid][0] = s1; red[wid][1] = s2; }
    __syncthreads();
    if (tid == 0) {
        double a1 = red[0][0] + red[1][0] + red[2][0] + red[3][0];
        double a2 = red[0][1] + red[1][1] + red[2][1] + red[3][1];
        double mean = a1 / (double)N_TOT;
        double var = a2 / (double)N_TOT - mean * mean;
        stats[0] = (float)mean;
        stats[1] = (float)(1.0 / sqrt(var + 1e-5));
    }
}

// ---------------------------------------------------------------------------
// Kernel D: in-place norm-affine + gelu, float4 vectorized
// ---------------------------------------------------------------------------
__global__ __launch_bounds__(256) void finalize_kernel(float* __restrict__ y,
                                                       const float* __restrict__ stats,
                                                       const float* __restrict__ gnw,
                                                       const float* __restrict__ gnb) {
    const int i = blockIdx.x * 256 + threadIdx.x;  // float4 index
    const float mean = stats[0], istd = stats[1];
    const int c = i >> 14;
    const float scale = gnw[c] * istd;
    const float shift = gnb[c] - mean * scale;
    float4 v = reinterpret_cast<float4*>(y)[i];
    v.x = gelu_f(fmaf(v.x, scale, shift));
    v.y = gelu_f(fmaf(v.y, scale, shift));
    v.z = gelu_f(fmaf(v.z, scale, shift));
    v.w = gelu_f(fmaf(v.w, scale, shift));
    reinterpret_cast<float4*>(y)[i] = v;
}

extern "C" void kernel_launch(void* const* d_in, const int* in_sizes, int n_in,
                              void* d_out, int out_size, void* d_ws, size_t ws_size,
                              hipStream_t stream) {
    const float* x   = (const float*)d_in[0];
    const float* cw  = (const float*)d_in[1];
    const float* cb  = (const float*)d_in[2];
    const float* bp  = (const float*)d_in[3];
    const float* Wm  = (const float*)d_in[4];
    const float* gnw = (const float*)d_in[5];
    const float* gnb = (const float*)d_in[6];
    float* out = (float*)d_out;

    char* ws = (char*)d_ws;
    float* alpha     = (float*)ws;                 // 64 floats
    float* stats     = (float*)(ws + 256);         // 2 floats
    double* partials = (double*)(ws + 512);        // CONV_BLOCKS*2 doubles

    alpha_kernel<<<64, 64, 0, stream>>>(bp, Wm, alpha);

    if (ws_size >= (size_t)WS_PAD_OFF + PAD_BYTES) {
        float* xpad = (float*)(ws + WS_PAD_OFF);   // padded x copy (17.97MB)
        pad_kernel<<<PAD_TOT / 256, 256, 0, stream>>>(x, xpad);
        conv_kernel<<<CONV_BLOCKS, 256, 0, stream>>>(xpad, cw, cb, alpha, out, partials);
    } else {
        float* zbuf = (float*)(ws + 32768);        // 256B zero page
        hipMemsetAsync(zbuf, 0, 256, stream);
        conv_fb<<<CONV_BLOCKS, 256, 0, stream>>>(x, cw, cb, alpha, zbuf, out, partials);
    }

    stats_kernel<<<1, 256, 0, stream>>>(partials, stats);
    finalize_kernel<<<4096, 256, 0, stream>>>(out, stats, gnw, gnb);
}